// Round 3
// baseline (241.378 us; speedup 1.0000x reference)
//
#include <hip/hip_runtime.h>
#include <hip/hip_bf16.h>

// Flash attention fwd. Inputs q[B,N,D], k[B,D,N] (=K^T), v[B,N,D] fp32,
// output fp32. B=16, N=2048, D=128.
// Precision scheme: Q,K split into bf16 hi+lo (x ~= hi + lo, lo exact
// residual); S = qh*kh + ql*kh + qh*kl via 3 MFMAs -> ~fp32-accurate scores.
// P and V single bf16 (error ~0.01 << 0.099 threshold).
// Block = 256 threads (4 waves), 64 q rows per block (16 per wave),
// 32 key tiles of BN=64, online softmax, fp32 accumulate.
// MFMA 16x16x32 bf16 verified layouts (learn_hip m89/m91/m120):
//   A: lane holds A[m=lane&15][k=(lane>>4)*8+j]
//   B: lane holds B[k=(lane>>4)*8+j][n=lane&15]
//   C/D: lane reg r holds C[row=(lane>>4)*4+r][col=lane&15]
// K/V transposed into LDS with 16B-granule XOR swizzle; staging packs bf16
// pairs along the transpose dim -> ds_write_b32, 2-way banks (free, m136).

typedef __attribute__((ext_vector_type(8))) short bf16x8;
typedef __attribute__((ext_vector_type(4))) float f32x4;

constexpr int Bz = 16;
constexpr int Nn = 2048;
constexpr int Dd = 128;
constexpr int BM = 64;   // q rows per block
constexpr int BN = 64;   // keys per iteration

__device__ __forceinline__ int swz(int r) { return (r ^ (r >> 3)) & 7; }

__device__ __forceinline__ uint f2bf_u(float f) {
    union { float f; uint u; } c; c.f = f;
    return (c.u + 0x7fffu + ((c.u >> 16) & 1u)) >> 16;   // RNE, finite
}
__device__ __forceinline__ ushort f2bf(float f) { return (ushort)f2bf_u(f); }
__device__ __forceinline__ float bf2f(ushort h) {
    union { float f; uint u; } c; c.u = ((uint)h) << 16;
    return c.f;
}
__device__ __forceinline__ uint pack2(float lo, float hi) {
    return f2bf_u(lo) | (f2bf_u(hi) << 16);
}

__global__ __launch_bounds__(256, 2)
void fattn_kernel(const float* __restrict__ qg,
                  const float* __restrict__ kg,
                  const float* __restrict__ vg,
                  float* __restrict__ og)
{
    __shared__ ushort lds_kh[BN * Dd];    // K hi: [kk][d ^ (swz(kk)<<3)] 16 KB
    __shared__ ushort lds_kl[BN * Dd];    // K lo: same layout            16 KB
    __shared__ ushort lds_v[Dd * BN];     // V:    [d][kk ^ (swz(d)<<3)]  16 KB
    __shared__ ushort lds_p[4][16 * BN];  // per-wave P scratch            8 KB
    uint* const lds_kh32 = (uint*)lds_kh;
    uint* const lds_kl32 = (uint*)lds_kl;
    uint* const lds_v32  = (uint*)lds_v;

    const int bid  = blockIdx.x;          // 512 blocks
    const int b    = bid >> 5;            // batch
    const int q0   = (bid & 31) * BM;     // q tile base
    const int tid  = threadIdx.x;
    const int wv   = tid >> 6;
    const int lane = tid & 63;
    const int quad = lane >> 4;
    const int l15  = lane & 15;

    // ---- Q fragments (A operand): hi + lo bf16 split, in registers ----
    bf16x8 qfh[4], qfl[4];
    {
        const float* qp = qg + (size_t)(b * Nn + q0 + wv * 16 + l15) * Dd + quad * 8;
        #pragma unroll
        for (int c = 0; c < 4; ++c) {
            float4 x0 = *(const float4*)(qp + c * 32);
            float4 x1 = *(const float4*)(qp + c * 32 + 4);
            const float xv[8] = {x0.x, x0.y, x0.z, x0.w, x1.x, x1.y, x1.z, x1.w};
            union { bf16x8 v; ushort e[8]; } uh, ul;
            #pragma unroll
            for (int j = 0; j < 8; ++j) {
                const ushort h = f2bf(xv[j]);
                uh.e[j] = h;
                ul.e[j] = f2bf(xv[j] - bf2f(h));   // exact residual (Sterbenz)
            }
            qfh[c] = uh.v; qfl[c] = ul.v;
        }
    }

    f32x4 accO[8];
    #pragma unroll
    for (int i = 0; i < 8; ++i) accO[i] = f32x4{0.f, 0.f, 0.f, 0.f};
    float m_i[4], l_i[4];
    #pragma unroll
    for (int r = 0; r < 4; ++r) { m_i[r] = -1e30f; l_i[r] = 0.f; }

    // staging thread mapping (constant across iterations)
    const int kgrp = tid & 7;    // K: n-group (8 n's)
    const int krow = tid >> 3;   // K: d-pair 0..31
    const int vgrp = tid & 15;   // V: d-group (8 d's)
    const int vrow = tid >> 4;   // V: kk-pair 0..15

    for (int n0 = 0; n0 < Nn; n0 += BN) {
        // ---- stage K tile: fp32 [d][n] -> lds_kh/lds_kl [n][d^sw] ----
        #pragma unroll
        for (int pass = 0; pass < 2; ++pass) {
            const int d0 = krow * 2 + pass * 64;               // even
            const float* s0 = kg + (size_t)(b * Dd + d0) * Nn + n0 + kgrp * 8;
            const float* s1 = s0 + Nn;                         // row d0+1
            float4 a0 = ((const float4*)s0)[0], a1 = ((const float4*)s0)[1];
            float4 b0 = ((const float4*)s1)[0], b1 = ((const float4*)s1)[1];
            const float av[8] = {a0.x, a0.y, a0.z, a0.w, a1.x, a1.y, a1.z, a1.w};
            const float bv[8] = {b0.x, b0.y, b0.z, b0.w, b1.x, b1.y, b1.z, b1.w};
            #pragma unroll
            for (int j = 0; j < 8; ++j) {
                const int n = kgrp * 8 + j;
                const int idx = n * (Dd / 2) + ((d0 >> 1) ^ (swz(n) << 2));
                const ushort ahi = f2bf(av[j]);
                const ushort bhi = f2bf(bv[j]);
                lds_kh32[idx] = (uint)ahi | ((uint)bhi << 16);
                const ushort alo = f2bf(av[j] - bf2f(ahi));
                const ushort blo = f2bf(bv[j] - bf2f(bhi));
                lds_kl32[idx] = (uint)alo | ((uint)blo << 16);
            }
        }
        // ---- stage V tile: fp32 [kk][d] -> lds_v[d][kk^sw] bf16 ----
        #pragma unroll
        for (int pass = 0; pass < 2; ++pass) {
            const int kk0 = vrow * 2 + pass * 32;              // even
            const float* s0 = vg + (size_t)(b * Nn + n0 + kk0) * Dd + vgrp * 8;
            const float* s1 = s0 + Dd;                         // row kk0+1
            float4 a0 = ((const float4*)s0)[0], a1 = ((const float4*)s0)[1];
            float4 b0 = ((const float4*)s1)[0], b1 = ((const float4*)s1)[1];
            const float av[8] = {a0.x, a0.y, a0.z, a0.w, a1.x, a1.y, a1.z, a1.w};
            const float bv[8] = {b0.x, b0.y, b0.z, b0.w, b1.x, b1.y, b1.z, b1.w};
            #pragma unroll
            for (int j = 0; j < 8; ++j) {
                const int dd = vgrp * 8 + j;
                lds_v32[dd * (BN / 2) + ((kk0 >> 1) ^ (swz(dd) << 2))] = pack2(av[j], bv[j]);
            }
        }
        __syncthreads();

        // ---- S = Q * K^T : 4 tiles, K-dim 128 in 4 chunks, 3-MFMA split ----
        f32x4 accS[4];
        #pragma unroll
        for (int kt = 0; kt < 4; ++kt) {
            f32x4 s = f32x4{0.f, 0.f, 0.f, 0.f};
            const int row = kt * 16 + l15;          // kk index (B-frag n)
            const int sw = swz(row) << 3;
            #pragma unroll
            for (int c = 0; c < 4; ++c) {
                const int off = row * Dd + ((c * 32 + quad * 8) ^ sw);
                bf16x8 kfh = *(const bf16x8*)&lds_kh[off];
                bf16x8 kfl = *(const bf16x8*)&lds_kl[off];
                s = __builtin_amdgcn_mfma_f32_16x16x32_bf16(qfh[c], kfh, s, 0, 0, 0);
                s = __builtin_amdgcn_mfma_f32_16x16x32_bf16(qfl[c], kfh, s, 0, 0, 0);
                s = __builtin_amdgcn_mfma_f32_16x16x32_bf16(qfh[c], kfl, s, 0, 0, 0);
            }
            accS[kt] = s;
        }

        // ---- online softmax (row = quad*4 + r) ----
        float tmax[4];
        #pragma unroll
        for (int r = 0; r < 4; ++r)
            tmax[r] = fmaxf(fmaxf(accS[0][r], accS[1][r]), fmaxf(accS[2][r], accS[3][r]));
        #pragma unroll
        for (int off = 1; off < 16; off <<= 1) {
            #pragma unroll
            for (int r = 0; r < 4; ++r)
                tmax[r] = fmaxf(tmax[r], __shfl_xor(tmax[r], off, 64));
        }
        float alpha[4];
        #pragma unroll
        for (int r = 0; r < 4; ++r) {
            const float mn = fmaxf(m_i[r], tmax[r]);
            alpha[r] = __expf(m_i[r] - mn);
            m_i[r] = mn;
        }
        float rsum[4] = {0.f, 0.f, 0.f, 0.f};
        #pragma unroll
        for (int kt = 0; kt < 4; ++kt) {
            #pragma unroll
            for (int r = 0; r < 4; ++r) {
                const float p = __expf(accS[kt][r] - m_i[r]);
                accS[kt][r] = p;
                rsum[r] += p;
            }
        }
        #pragma unroll
        for (int off = 1; off < 16; off <<= 1) {
            #pragma unroll
            for (int r = 0; r < 4; ++r)
                rsum[r] += __shfl_xor(rsum[r], off, 64);
        }
        #pragma unroll
        for (int r = 0; r < 4; ++r)
            l_i[r] = l_i[r] * alpha[r] + rsum[r];

        // rescale O accumulator
        #pragma unroll
        for (int dt = 0; dt < 8; ++dt) {
            #pragma unroll
            for (int r = 0; r < 4; ++r)
                accO[dt][r] *= alpha[r];
        }

        // ---- P (C layout) -> LDS -> A-operand layout (wave-private) ----
        ushort* pl = &lds_p[wv][0];
        #pragma unroll
        for (int kt = 0; kt < 4; ++kt) {
            #pragma unroll
            for (int r = 0; r < 4; ++r) {
                const int row = quad * 4 + r;
                const int col = kt * 16 + l15;
                pl[row * BN + (col ^ (swz(row) << 3))] = f2bf(accS[kt][r]);
            }
        }
        bf16x8 pf[2];
        {
            const int row = l15;
            const int sw = swz(row) << 3;
            pf[0] = *(const bf16x8*)&pl[row * BN + ((quad * 8) ^ sw)];
            pf[1] = *(const bf16x8*)&pl[row * BN + ((32 + quad * 8) ^ sw)];
        }

        // ---- O += P * V : 8 dout tiles, K-dim 64 in 2 chunks ----
        #pragma unroll
        for (int dt = 0; dt < 8; ++dt) {
            const int row = dt * 16 + l15;          // dout index (B-frag n)
            const int sw = swz(row) << 3;
            bf16x8 vf0 = *(const bf16x8*)&lds_v[row * BN + ((quad * 8) ^ sw)];
            bf16x8 vf1 = *(const bf16x8*)&lds_v[row * BN + ((32 + quad * 8) ^ sw)];
            accO[dt] = __builtin_amdgcn_mfma_f32_16x16x32_bf16(pf[0], vf0, accO[dt], 0, 0, 0);
            accO[dt] = __builtin_amdgcn_mfma_f32_16x16x32_bf16(pf[1], vf1, accO[dt], 0, 0, 0);
        }
        __syncthreads();   // protect lds_k/lds_v before next staging
    }

    // ---- epilogue: O / l, fp32 store ----
    float inv[4];
    #pragma unroll
    for (int r = 0; r < 4; ++r) inv[r] = 1.f / l_i[r];
    float* ob = og + (size_t)(b * Nn + q0 + wv * 16) * Dd;
    #pragma unroll
    for (int dt = 0; dt < 8; ++dt) {
        #pragma unroll
        for (int r = 0; r < 4; ++r) {
            const int row = quad * 4 + r;
            const int col = dt * 16 + l15;
            ob[(size_t)row * Dd + col] = accO[dt][r] * inv[r];
        }
    }
}

extern "C" void kernel_launch(void* const* d_in, const int* in_sizes, int n_in,
                              void* d_out, int out_size, void* d_ws, size_t ws_size,
                              hipStream_t stream) {
    const float* q = (const float*)d_in[0];
    const float* k = (const float*)d_in[1];
    const float* v = (const float*)d_in[2];
    float* o = (float*)d_out;
    (void)d_ws; (void)ws_size; (void)in_sizes; (void)n_in; (void)out_size;
    fattn_kernel<<<dim3(Bz * (Nn / BM)), dim3(256), 0, stream>>>(q, k, v, o);
}

// Round 4
// 196.456 us; speedup vs baseline: 1.2287x; 1.2287x over previous
//
#include <hip/hip_runtime.h>
#include <hip/hip_bf16.h>

// Flash attention fwd. Inputs q[B,N,D], k[B,D,N] (=K^T), v[B,N,D] fp32,
// output fp32. B=16, N=2048, D=128.
// R4: fp16 MFMA path (10 mantissa bits -> single-term QK^T suffices;
// measured 1-term bf16 absmax 0.143 -> /8 ulp ratio ~0.018).
// Block = 256 threads (4 waves), 64 q rows per block (16 per wave),
// 32 key tiles of BN=64, online softmax, fp32 accumulate.
// MFMA 16x16x32 (layouts verified learn_hip m89/m91/m120, dtype-indep C/D):
//   A: lane holds A[m=lane&15][k=(lane>>4)*8+j]
//   B: lane holds B[k=(lane>>4)*8+j][n=lane&15]
//   C/D: lane reg r holds C[row=(lane>>4)*4+r][col=lane&15]
// K/V transposed into LDS with 16B-granule XOR swizzle (2-way banks, free).
// P scratch uses swzP(row)=(row>>1)&6 -> write banks fully disjoint per quad.
// Reductions via DPP (quad_perm/row_ror), no LDS; l-reduction deferred to
// epilogue (alpha is row-uniform so per-lane partials are exact).

typedef __attribute__((ext_vector_type(8))) _Float16 f16x8;
typedef __attribute__((ext_vector_type(4))) float f32x4;

constexpr int Bz = 16;
constexpr int Nn = 2048;
constexpr int Dd = 128;
constexpr int BM = 64;   // q rows per block
constexpr int BN = 64;   // keys per iteration

__device__ __forceinline__ int swz(int r) { return (r ^ (r >> 3)) & 7; }
__device__ __forceinline__ int swzP(int row) { return (row >> 1) & 6; }

__device__ __forceinline__ uint packh2(float a, float b) {
    union { _Float16 h[2]; uint u; } p;
    p.h[0] = (_Float16)a; p.h[1] = (_Float16)b;
    return p.u;
}
__device__ __forceinline__ ushort f2h_bits(float a) {
    union { _Float16 h; ushort u; } p;
    p.h = (_Float16)a;
    return p.u;
}

template <int CTRL>
__device__ __forceinline__ float dpp_mov(float x) {
    int y = __builtin_amdgcn_mov_dpp(__builtin_bit_cast(int, x), CTRL, 0xF, 0xF, true);
    return __builtin_bit_cast(float, y);
}
// 16-lane all-reduce: xor1, xor2 (quad_perm), then row_ror:4, row_ror:8.
template <typename Op>
__device__ __forceinline__ float allred16(float x, Op op) {
    x = op(x, dpp_mov<0xB1>(x));    // quad_perm [1,0,3,2]
    x = op(x, dpp_mov<0x4E>(x));    // quad_perm [2,3,0,1]
    x = op(x, dpp_mov<0x124>(x));   // row_ror:4
    x = op(x, dpp_mov<0x128>(x));   // row_ror:8
    return x;
}

__global__ __launch_bounds__(256, 2)
void fattn_kernel(const float* __restrict__ qg,
                  const float* __restrict__ kg,
                  const float* __restrict__ vg,
                  float* __restrict__ og)
{
    __shared__ ushort lds_k[BN * Dd];     // [kk][d ^ (swz(kk)<<3)]  16 KB
    __shared__ ushort lds_v[Dd * BN];     // [d][kk ^ (swz(d)<<3)]   16 KB
    __shared__ ushort lds_p[4][16 * BN];  // per-wave P scratch        8 KB
    uint* const lds_k32 = (uint*)lds_k;
    uint* const lds_v32 = (uint*)lds_v;

    const int bid  = blockIdx.x;          // 512 blocks
    const int b    = bid >> 5;            // batch
    const int q0   = (bid & 31) * BM;     // q tile base
    const int tid  = threadIdx.x;
    const int wv   = tid >> 6;
    const int lane = tid & 63;
    const int quad = lane >> 4;
    const int l15  = lane & 15;

    // ---- Q fragments (A operand), fp32 -> fp16 RNE, kept in registers ----
    f16x8 qf[4];
    {
        const float* qp = qg + (size_t)(b * Nn + q0 + wv * 16 + l15) * Dd + quad * 8;
        #pragma unroll
        for (int c = 0; c < 4; ++c) {
            float4 x0 = *(const float4*)(qp + c * 32);
            float4 x1 = *(const float4*)(qp + c * 32 + 4);
            const float xv[8] = {x0.x, x0.y, x0.z, x0.w, x1.x, x1.y, x1.z, x1.w};
            union { f16x8 v; _Float16 e[8]; } u;
            #pragma unroll
            for (int j = 0; j < 8; ++j) u.e[j] = (_Float16)xv[j];
            qf[c] = u.v;
        }
    }

    f32x4 accO[8];
    #pragma unroll
    for (int i = 0; i < 8; ++i) accO[i] = f32x4{0.f, 0.f, 0.f, 0.f};
    float m_i[4], l_i[4];
    #pragma unroll
    for (int r = 0; r < 4; ++r) { m_i[r] = -1e30f; l_i[r] = 0.f; }

    // staging thread mapping (constant across iterations)
    const int kgrp = tid & 7;    // K: n-group (8 n's)
    const int krow = tid >> 3;   // K: d-pair 0..31
    const int vgrp = tid & 15;   // V: d-group (8 d's)
    const int vrow = tid >> 4;   // V: kk-pair 0..15

    for (int n0 = 0; n0 < Nn; n0 += BN) {
        // ---- stage K tile: fp32 [d][n] -> lds_k[n][d^sw] fp16 ----
        #pragma unroll
        for (int pass = 0; pass < 2; ++pass) {
            const int d0 = krow * 2 + pass * 64;               // even
            const float* s0 = kg + (size_t)(b * Dd + d0) * Nn + n0 + kgrp * 8;
            const float* s1 = s0 + Nn;                         // row d0+1
            float4 a0 = ((const float4*)s0)[0], a1 = ((const float4*)s0)[1];
            float4 b0 = ((const float4*)s1)[0], b1 = ((const float4*)s1)[1];
            const float av[8] = {a0.x, a0.y, a0.z, a0.w, a1.x, a1.y, a1.z, a1.w};
            const float bv[8] = {b0.x, b0.y, b0.z, b0.w, b1.x, b1.y, b1.z, b1.w};
            #pragma unroll
            for (int j = 0; j < 8; ++j) {
                const int n = kgrp * 8 + j;
                lds_k32[n * (Dd / 2) + ((d0 >> 1) ^ (swz(n) << 2))] = packh2(av[j], bv[j]);
            }
        }
        // ---- stage V tile: fp32 [kk][d] -> lds_v[d][kk^sw] fp16 ----
        #pragma unroll
        for (int pass = 0; pass < 2; ++pass) {
            const int kk0 = vrow * 2 + pass * 32;              // even
            const float* s0 = vg + (size_t)(b * Nn + n0 + kk0) * Dd + vgrp * 8;
            const float* s1 = s0 + Dd;                         // row kk0+1
            float4 a0 = ((const float4*)s0)[0], a1 = ((const float4*)s0)[1];
            float4 b0 = ((const float4*)s1)[0], b1 = ((const float4*)s1)[1];
            const float av[8] = {a0.x, a0.y, a0.z, a0.w, a1.x, a1.y, a1.z, a1.w};
            const float bv[8] = {b0.x, b0.y, b0.z, b0.w, b1.x, b1.y, b1.z, b1.w};
            #pragma unroll
            for (int j = 0; j < 8; ++j) {
                const int dd = vgrp * 8 + j;
                lds_v32[dd * (BN / 2) + ((kk0 >> 1) ^ (swz(dd) << 2))] = packh2(av[j], bv[j]);
            }
        }
        __syncthreads();

        // ---- S = Q * K^T : 4 tiles of 16x16, K-dim 128 in 4 chunks ----
        f32x4 accS[4];
        #pragma unroll
        for (int kt = 0; kt < 4; ++kt) {
            f32x4 s = f32x4{0.f, 0.f, 0.f, 0.f};
            const int row = kt * 16 + l15;          // kk index (B-frag n)
            const int sw = swz(row) << 3;
            #pragma unroll
            for (int c = 0; c < 4; ++c) {
                f16x8 kf = *(const f16x8*)&lds_k[row * Dd + ((c * 32 + quad * 8) ^ sw)];
                s = __builtin_amdgcn_mfma_f32_16x16x32_f16(qf[c], kf, s, 0, 0, 0);
            }
            accS[kt] = s;
        }

        // ---- online softmax (row = quad*4 + r), DPP reductions ----
        float alpha[4];
        #pragma unroll
        for (int r = 0; r < 4; ++r) {
            float t = fmaxf(fmaxf(accS[0][r], accS[1][r]), fmaxf(accS[2][r], accS[3][r]));
            t = allred16(t, [](float a, float bb) { return fmaxf(a, bb); });
            const float mn = fmaxf(m_i[r], t);
            alpha[r] = __expf(m_i[r] - mn);
            m_i[r] = mn;
        }
        #pragma unroll
        for (int r = 0; r < 4; ++r) {
            float local = 0.f;
            #pragma unroll
            for (int kt = 0; kt < 4; ++kt) {
                const float p = __expf(accS[kt][r] - m_i[r]);
                accS[kt][r] = p;
                local += p;
            }
            l_i[r] = l_i[r] * alpha[r] + local;   // per-lane partial; reduce at end
        }

        // rescale O accumulator
        #pragma unroll
        for (int dt = 0; dt < 8; ++dt) {
            #pragma unroll
            for (int r = 0; r < 4; ++r)
                accO[dt][r] *= alpha[r];
        }

        // ---- P (C layout) -> LDS -> A-operand layout (wave-private) ----
        ushort* pl = &lds_p[wv][0];
        #pragma unroll
        for (int kt = 0; kt < 4; ++kt) {
            #pragma unroll
            for (int r = 0; r < 4; ++r) {
                const int row = quad * 4 + r;
                const int col = kt * 16 + l15;
                pl[row * BN + (col ^ (swzP(row) << 3))] = f2h_bits(accS[kt][r]);
            }
        }
        f16x8 pf[2];
        {
            const int row = l15;
            const int sw = swzP(row) << 3;
            pf[0] = *(const f16x8*)&pl[row * BN + ((quad * 8) ^ sw)];
            pf[1] = *(const f16x8*)&pl[row * BN + ((32 + quad * 8) ^ sw)];
        }

        // ---- O += P * V : 8 dout tiles, K-dim 64 in 2 chunks ----
        #pragma unroll
        for (int dt = 0; dt < 8; ++dt) {
            const int row = dt * 16 + l15;          // dout index (B-frag n)
            const int sw = swz(row) << 3;
            f16x8 vf0 = *(const f16x8*)&lds_v[row * BN + ((quad * 8) ^ sw)];
            f16x8 vf1 = *(const f16x8*)&lds_v[row * BN + ((32 + quad * 8) ^ sw)];
            accO[dt] = __builtin_amdgcn_mfma_f32_16x16x32_f16(pf[0], vf0, accO[dt], 0, 0, 0);
            accO[dt] = __builtin_amdgcn_mfma_f32_16x16x32_f16(pf[1], vf1, accO[dt], 0, 0, 0);
        }
        __syncthreads();   // protect lds_k/lds_v before next staging
    }

    // ---- epilogue: reduce l across the 16 lanes of each row, O/l, store ----
    float inv[4];
    #pragma unroll
    for (int r = 0; r < 4; ++r) {
        const float l = allred16(l_i[r], [](float a, float bb) { return a + bb; });
        inv[r] = 1.f / l;
    }
    float* ob = og + (size_t)(b * Nn + q0 + wv * 16) * Dd;
    #pragma unroll
    for (int dt = 0; dt < 8; ++dt) {
        #pragma unroll
        for (int r = 0; r < 4; ++r) {
            const int row = quad * 4 + r;
            const int col = dt * 16 + l15;
            ob[(size_t)row * Dd + col] = accO[dt][r] * inv[r];
        }
    }
}

extern "C" void kernel_launch(void* const* d_in, const int* in_sizes, int n_in,
                              void* d_out, int out_size, void* d_ws, size_t ws_size,
                              hipStream_t stream) {
    const float* q = (const float*)d_in[0];
    const float* k = (const float*)d_in[1];
    const float* v = (const float*)d_in[2];
    float* o = (float*)d_out;
    (void)d_ws; (void)ws_size; (void)in_sizes; (void)n_in; (void)out_size;
    fattn_kernel<<<dim3(Bz * (Nn / BM)), dim3(256), 0, stream>>>(q, k, v, o);
}

// Round 5
// 158.584 us; speedup vs baseline: 1.5221x; 1.2388x over previous
//
#include <hip/hip_runtime.h>
#include <hip/hip_bf16.h>

// Flash attention fwd. q[B,N,D], k[B,D,N] (=K^T), v[B,N,D] fp32 in, fp32 out.
// B=16, N=2048, D=128. fp16 MFMA path, fp32 accumulate.
// R5: register-prefetch software pipeline (iter n+1 globals issued before
// iter n compute; vmcnt wait lands after compute) + XCD-aware block swizzle
// (batch-pair per XCD -> K/V working set ~4MB fits per-XCD L2).
// Block = 256 threads (4 waves), 64 q rows/block, 32 key tiles of BN=64,
// online softmax with DPP reductions, deferred l-reduction.
// MFMA 16x16x32 layouts (learn_hip m89/m91/m120, dtype-indep C/D):
//   A: lane holds A[m=lane&15][k=(lane>>4)*8+j]
//   B: lane holds B[k=(lane>>4)*8+j][n=lane&15]
//   C/D: lane reg r holds C[row=(lane>>4)*4+r][col=lane&15]
// K/V in LDS transposed, 16B-granule XOR swizzle (2-way banks = free, m136).
// P scratch swzP(row)=(row>>1)&6 -> conflict-free writes, balanced reads.

typedef __attribute__((ext_vector_type(8))) _Float16 f16x8;
typedef __attribute__((ext_vector_type(4))) float f32x4;

constexpr int Bz = 16;
constexpr int Nn = 2048;
constexpr int Dd = 128;
constexpr int BM = 64;   // q rows per block
constexpr int BN = 64;   // keys per iteration

__device__ __forceinline__ int swz(int r) { return (r ^ (r >> 3)) & 7; }
__device__ __forceinline__ int swzP(int row) { return (row >> 1) & 6; }

__device__ __forceinline__ uint packh2(float a, float b) {
    union { _Float16 h[2]; uint u; } p;
    p.h[0] = (_Float16)a; p.h[1] = (_Float16)b;
    return p.u;
}
__device__ __forceinline__ ushort f2h_bits(float a) {
    union { _Float16 h; ushort u; } p;
    p.h = (_Float16)a;
    return p.u;
}

template <int CTRL>
__device__ __forceinline__ float dpp_mov(float x) {
    int y = __builtin_amdgcn_mov_dpp(__builtin_bit_cast(int, x), CTRL, 0xF, 0xF, true);
    return __builtin_bit_cast(float, y);
}
// 16-lane all-reduce: quad_perm xor1/xor2, then row_ror:4, row_ror:8.
template <typename Op>
__device__ __forceinline__ float allred16(float x, Op op) {
    x = op(x, dpp_mov<0xB1>(x));    // quad_perm [1,0,3,2]
    x = op(x, dpp_mov<0x4E>(x));    // quad_perm [2,3,0,1]
    x = op(x, dpp_mov<0x124>(x));   // row_ror:4
    x = op(x, dpp_mov<0x128>(x));   // row_ror:8
    return x;
}

__global__ __launch_bounds__(256, 2)
void fattn_kernel(const float* __restrict__ qg,
                  const float* __restrict__ kg,
                  const float* __restrict__ vg,
                  float* __restrict__ og)
{
    __shared__ ushort lds_k[BN * Dd];     // [kk][d ^ (swz(kk)<<3)]  16 KB
    __shared__ ushort lds_v[Dd * BN];     // [d][kk ^ (swz(d)<<3)]   16 KB
    __shared__ ushort lds_p[4][16 * BN];  // per-wave P scratch        8 KB
    uint* const lds_k32 = (uint*)lds_k;
    uint* const lds_v32 = (uint*)lds_v;

    // XCD-aware swizzle: assume dispatch XCD = blockIdx.x % 8 (perf-only
    // heuristic). XCD x serves batches {2x, 2x+1}: K+V fp32 working set
    // = 4 MB = per-XCD L2.
    const int bid  = blockIdx.x;          // 512 blocks
    const int xcd  = bid & 7;
    const int idx  = bid >> 3;            // 0..63
    const int b    = xcd * 2 + (idx >> 5);
    const int q0   = (idx & 31) * BM;
    const int tid  = threadIdx.x;
    const int wv   = tid >> 6;
    const int lane = tid & 63;
    const int quad = lane >> 4;
    const int l15  = lane & 15;

    // ---- Q fragments (A operand), fp32 -> fp16 RNE, kept in registers ----
    f16x8 qf[4];
    {
        const float* qp = qg + (size_t)(b * Nn + q0 + wv * 16 + l15) * Dd + quad * 8;
        #pragma unroll
        for (int c = 0; c < 4; ++c) {
            float4 x0 = *(const float4*)(qp + c * 32);
            float4 x1 = *(const float4*)(qp + c * 32 + 4);
            const float xv[8] = {x0.x, x0.y, x0.z, x0.w, x1.x, x1.y, x1.z, x1.w};
            union { f16x8 v; _Float16 e[8]; } u;
            #pragma unroll
            for (int j = 0; j < 8; ++j) u.e[j] = (_Float16)xv[j];
            qf[c] = u.v;
        }
    }

    f32x4 accO[8];
    #pragma unroll
    for (int i = 0; i < 8; ++i) accO[i] = f32x4{0.f, 0.f, 0.f, 0.f};
    float m_i[4], l_i[4];
    #pragma unroll
    for (int r = 0; r < 4; ++r) { m_i[r] = -1e30f; l_i[r] = 0.f; }

    // staging thread mapping (constant across iterations)
    const int kgrp = tid & 7;    // K: n-group (8 n's)
    const int krow = tid >> 3;   // K: d-pair 0..31
    const int vgrp = tid & 15;   // V: d-group (8 d's)
    const int vrow = tid >> 4;   // V: kk-pair 0..15

    const float* kbase = kg + (size_t)b * Dd * Nn;
    const float* vbase = vg + (size_t)b * Nn * Dd;

    // prefetch register buffers: 16 float4 in flight across compute
    float4 kr[8], vr[8];
    auto issue_loads = [&](int n0) {
        #pragma unroll
        for (int pass = 0; pass < 2; ++pass) {
            const int d0 = krow * 2 + pass * 64;
            const float* s0 = kbase + (size_t)d0 * Nn + n0 + kgrp * 8;
            kr[pass * 4 + 0] = ((const float4*)s0)[0];
            kr[pass * 4 + 1] = ((const float4*)s0)[1];
            kr[pass * 4 + 2] = ((const float4*)(s0 + Nn))[0];
            kr[pass * 4 + 3] = ((const float4*)(s0 + Nn))[1];
            const int kk0 = vrow * 2 + pass * 32;
            const float* t0 = vbase + (size_t)(n0 + kk0) * Dd + vgrp * 8;
            vr[pass * 4 + 0] = ((const float4*)t0)[0];
            vr[pass * 4 + 1] = ((const float4*)t0)[1];
            vr[pass * 4 + 2] = ((const float4*)(t0 + Dd))[0];
            vr[pass * 4 + 3] = ((const float4*)(t0 + Dd))[1];
        }
    };
    auto write_lds = [&]() {
        #pragma unroll
        for (int pass = 0; pass < 2; ++pass) {
            const int d0 = krow * 2 + pass * 64;
            const float* av = (const float*)&kr[pass * 4 + 0];  // row d0
            const float* bv = (const float*)&kr[pass * 4 + 2];  // row d0+1
            #pragma unroll
            for (int j = 0; j < 8; ++j) {
                const int n = kgrp * 8 + j;
                lds_k32[n * (Dd / 2) + ((d0 >> 1) ^ (swz(n) << 2))] = packh2(av[j], bv[j]);
            }
            const int kk0 = vrow * 2 + pass * 32;
            const float* cv = (const float*)&vr[pass * 4 + 0];  // row kk0
            const float* dv = (const float*)&vr[pass * 4 + 2];  // row kk0+1
            #pragma unroll
            for (int j = 0; j < 8; ++j) {
                const int dd = vgrp * 8 + j;
                lds_v32[dd * (BN / 2) + ((kk0 >> 1) ^ (swz(dd) << 2))] = packh2(cv[j], dv[j]);
            }
        }
    };

    issue_loads(0);

    for (int it = 0; it < Nn / BN; ++it) {
        write_lds();          // vmcnt wait on kr/vr happens here
        __syncthreads();

        // prefetch next tile into registers; overlaps with compute below.
        // (it==31 wraps to tile 0: dead load, keeps the loop branch-free)
        issue_loads(((it + 1) & 31) * BN);

        // ---- S = Q * K^T : 4 tiles of 16x16, K-dim 128 in 4 chunks ----
        f32x4 accS[4];
        #pragma unroll
        for (int kt = 0; kt < 4; ++kt) {
            f32x4 s = f32x4{0.f, 0.f, 0.f, 0.f};
            const int row = kt * 16 + l15;          // kk index (B-frag n)
            const int sw = swz(row) << 3;
            #pragma unroll
            for (int c = 0; c < 4; ++c) {
                f16x8 kf = *(const f16x8*)&lds_k[row * Dd + ((c * 32 + quad * 8) ^ sw)];
                s = __builtin_amdgcn_mfma_f32_16x16x32_f16(qf[c], kf, s, 0, 0, 0);
            }
            accS[kt] = s;
        }

        // ---- online softmax (row = quad*4 + r), DPP reductions ----
        float alpha[4];
        #pragma unroll
        for (int r = 0; r < 4; ++r) {
            float t = fmaxf(fmaxf(accS[0][r], accS[1][r]), fmaxf(accS[2][r], accS[3][r]));
            t = allred16(t, [](float a, float bb) { return fmaxf(a, bb); });
            const float mn = fmaxf(m_i[r], t);
            alpha[r] = __expf(m_i[r] - mn);
            m_i[r] = mn;
        }
        #pragma unroll
        for (int r = 0; r < 4; ++r) {
            float local = 0.f;
            #pragma unroll
            for (int kt = 0; kt < 4; ++kt) {
                const float p = __expf(accS[kt][r] - m_i[r]);
                accS[kt][r] = p;
                local += p;
            }
            l_i[r] = l_i[r] * alpha[r] + local;   // per-lane partial
        }

        // rescale O accumulator
        #pragma unroll
        for (int dt = 0; dt < 8; ++dt) {
            #pragma unroll
            for (int r = 0; r < 4; ++r)
                accO[dt][r] *= alpha[r];
        }

        // ---- P (C layout) -> LDS -> A-operand layout (wave-private) ----
        ushort* pl = &lds_p[wv][0];
        #pragma unroll
        for (int kt = 0; kt < 4; ++kt) {
            #pragma unroll
            for (int r = 0; r < 4; ++r) {
                const int row = quad * 4 + r;
                const int col = kt * 16 + l15;
                pl[row * BN + (col ^ (swzP(row) << 3))] = f2h_bits(accS[kt][r]);
            }
        }
        f16x8 pf[2];
        {
            const int row = l15;
            const int sw = swzP(row) << 3;
            pf[0] = *(const f16x8*)&pl[row * BN + ((quad * 8) ^ sw)];
            pf[1] = *(const f16x8*)&pl[row * BN + ((32 + quad * 8) ^ sw)];
        }

        // ---- O += P * V : 8 dout tiles, K-dim 64 in 2 chunks ----
        #pragma unroll
        for (int dt = 0; dt < 8; ++dt) {
            const int row = dt * 16 + l15;          // dout index (B-frag n)
            const int sw = swz(row) << 3;
            f16x8 vf0 = *(const f16x8*)&lds_v[row * BN + ((quad * 8) ^ sw)];
            f16x8 vf1 = *(const f16x8*)&lds_v[row * BN + ((32 + quad * 8) ^ sw)];
            accO[dt] = __builtin_amdgcn_mfma_f32_16x16x32_f16(pf[0], vf0, accO[dt], 0, 0, 0);
            accO[dt] = __builtin_amdgcn_mfma_f32_16x16x32_f16(pf[1], vf1, accO[dt], 0, 0, 0);
        }
        __syncthreads();   // all waves done reading lds_k/lds_v
    }

    // ---- epilogue: reduce l across 16 lanes of each row, O/l, store ----
    float inv[4];
    #pragma unroll
    for (int r = 0; r < 4; ++r) {
        const float l = allred16(l_i[r], [](float a, float bb) { return a + bb; });
        inv[r] = 1.f / l;
    }
    float* ob = og + (size_t)(b * Nn + q0 + wv * 16) * Dd;
    #pragma unroll
    for (int dt = 0; dt < 8; ++dt) {
        #pragma unroll
        for (int r = 0; r < 4; ++r) {
            const int row = quad * 4 + r;
            const int col = dt * 16 + l15;
            ob[(size_t)row * Dd + col] = accO[dt][r] * inv[r];
        }
    }
}

extern "C" void kernel_launch(void* const* d_in, const int* in_sizes, int n_in,
                              void* d_out, int out_size, void* d_ws, size_t ws_size,
                              hipStream_t stream) {
    const float* q = (const float*)d_in[0];
    const float* k = (const float*)d_in[1];
    const float* v = (const float*)d_in[2];
    float* o = (float*)d_out;
    (void)d_ws; (void)ws_size; (void)in_sizes; (void)n_in; (void)out_size;
    fattn_kernel<<<dim3(Bz * (Nn / BM)), dim3(256), 0, stream>>>(q, k, v, o);
}